// Round 1
// baseline (4997.983 us; speedup 1.0000x reference)
//
#include <hip/hip_runtime.h>
#include <math.h>

#define Bz 32
#define Tz 50
#define Sz 40
#define Vz 32000
#define Dz 512
#define Hz 1024
#define KXz 1536   // D + H
#define K2z 2048   // 2H
#define KSPL 8

// workspace layout (float offsets)
#define OFF_XHT 0                              // [2][1536][32]  xh transposed, double buffered
#define OFF_CX   (OFF_XHT + 2*KXz*Bz)          // [32][1024]     cell state row-major
#define OFF_CTXT (OFF_CX + Bz*Hz)              // [1024][32]     ctx transposed
#define OFF_GP   (OFF_CTXT + Hz*Bz)            // [32][8][4096]  gates partials
#define OFF_HP   (OFF_GP + Bz*KSPL*4*Hz)       // [32][8][1024]  ht partials
#define OFF_HXA  (OFF_HP + Bz*KSPL*Hz)         // [50][32][1024] attention-combined hidden

__global__ __launch_bounds__(256) void k_init(float* ws, const int* tok, const float* emb,
                                              const float* h0, const float* c0) {
    int gid = blockIdx.x * 256 + threadIdx.x;
    if (gid < KXz * Bz) {
        int k = gid >> 5, b = gid & 31;
        float v;
        if (k < Dz) v = emb[(long)tok[b * Tz] * Dz + k];
        else        v = h0[b * Hz + (k - Dz)];
        ws[OFF_XHT + k * Bz + b] = v;
    } else {
        int g2 = gid - KXz * Bz;
        if (g2 < Bz * Hz) ws[OFF_CX + g2] = c0[g2];
    }
}

// k_A: gates partials (wgs 0..511) + attention-combine partials for step t-1 (wgs 512..639)
__global__ __launch_bounds__(256) void k_A(float* ws, const float* Wih, const float* Whh,
                                           const float* Wht, int t, int do_gates, int do_ht) {
    int wid = blockIdx.x, tid = threadIdx.x;
    int wave = tid >> 6, lane = tid & 63;
    int b = lane & 31, jh = lane >> 5;
    int p = t & 1;
    const float* xh = ws + OFF_XHT + p * KXz * Bz;

    if (wid < 512) {
        if (!do_gates) return;
        int jt = wid >> 3, ks = wid & 7;
        int j0 = jt * 64 + wave * 16 + jh * 8;
        int kbeg = ks * 192;
        float acc[8];
#pragma unroll
        for (int i = 0; i < 8; i++) acc[i] = 0.f;
        for (int kb = 0; kb < 192; kb += 8) {
            int kk = kbeg + kb;
            float x[8];
#pragma unroll
            for (int u = 0; u < 8; u++) x[u] = xh[(kk + u) * Bz + b];
#pragma unroll
            for (int jj = 0; jj < 8; jj++) {
                int j = j0 + jj;
                const float* wr = (kk < Dz) ? (Wih + (long)j * Dz + kk)
                                            : (Whh + (long)j * Hz + (kk - Dz));
                float4 w0 = *(const float4*)wr;
                float4 w1 = *(const float4*)(wr + 4);
                acc[jj] += x[0]*w0.x + x[1]*w0.y + x[2]*w0.z + x[3]*w0.w
                         + x[4]*w1.x + x[5]*w1.y + x[6]*w1.z + x[7]*w1.w;
            }
        }
        float* gp = ws + OFF_GP + ((long)b * KSPL + ks) * (4*Hz) + j0;
        float4 s0 = {acc[0], acc[1], acc[2], acc[3]};
        float4 s1 = {acc[4], acc[5], acc[6], acc[7]};
        *(float4*)gp = s0; *(float4*)(gp + 4) = s1;
    } else {
        if (!do_ht) return;
        int widh = wid - 512;
        int jt = widh >> 3, ks = widh & 7;
        int h0i = jt * 64 + wave * 16 + jh * 8;
        int kbeg = ks * 256;
        const float* ctxT = ws + OFF_CTXT;
        float acc[8];
#pragma unroll
        for (int i = 0; i < 8; i++) acc[i] = 0.f;
        for (int kb = 0; kb < 256; kb += 8) {
            int kk = kbeg + kb;
            const float* xb = (kk < Hz) ? (ctxT + kk * Bz) : (xh + (Dz + kk - Hz) * Bz);
            float x[8];
#pragma unroll
            for (int u = 0; u < 8; u++) x[u] = xb[u * Bz + b];
#pragma unroll
            for (int jj = 0; jj < 8; jj++) {
                const float* wr = Wht + (long)(h0i + jj) * K2z + kk;
                float4 w0 = *(const float4*)wr;
                float4 w1 = *(const float4*)(wr + 4);
                acc[jj] += x[0]*w0.x + x[1]*w0.y + x[2]*w0.z + x[3]*w0.w
                         + x[4]*w1.x + x[5]*w1.y + x[6]*w1.z + x[7]*w1.w;
            }
        }
        float* hp = ws + OFF_HP + ((long)b * KSPL + ks) * Hz + h0i;
        float4 s0 = {acc[0], acc[1], acc[2], acc[3]};
        float4 s1 = {acc[4], acc[5], acc[6], acc[7]};
        *(float4*)hp = s0; *(float4*)(hp + 4) = s1;
    }
}

__device__ __forceinline__ float sigf(float x) { return 1.f / (1.f + expf(-x)); }

// k_B: wgs 0..31 cell+attention (one per batch b); 32..159 combine-reduce -> HXA[t-1];
//      160..223 embedding gather for step t+1
__global__ __launch_bounds__(256) void k_B(float* ws, const float* bih, const float* bhh,
                                           const float* enc, const float* emb, const int* tok,
                                           const float* bht, int t, int do_cell, int do_htred,
                                           int do_gather) {
    int wid = blockIdx.x, tid = threadIdx.x;
    int p = t & 1;
    if (wid < 32) {
        if (!do_cell) return;
        __shared__ float hxs[Hz];
        __shared__ float sc[Sz];
        __shared__ float aw[Sz];
        int b = wid;
        // reduce gate partials + biases
        float gs[16];
        const float* gp = ws + OFF_GP + (long)b * KSPL * (4*Hz);
#pragma unroll
        for (int m = 0; m < 16; m++) {
            int j = tid + 256 * m;
            float s = 0.f;
#pragma unroll
            for (int ks = 0; ks < KSPL; ks++) s += gp[ks * (4*Hz) + j];
            gs[m] = s + bih[j] + bhh[j];
        }
        float* cx  = ws + OFF_CX + (long)b * Hz;
        float* xhn = ws + OFF_XHT + (p ^ 1) * KXz * Bz;
#pragma unroll
        for (int r = 0; r < 4; r++) {
            int h = tid + 256 * r;
            float ig = sigf(gs[r]);
            float fg = sigf(gs[4 + r]);
            float gg = tanhf(gs[8 + r]);
            float og = sigf(gs[12 + r]);
            float c  = fg * cx[h] + ig * gg;
            float hv = og * tanhf(c);
            cx[h] = c;
            xhn[(Dz + h) * Bz + b] = hv;
            hxs[h] = hv;
        }
        __syncthreads();
        // attention scores
        int wave = tid >> 6, lane = tid & 63;
        float hreg[16];
#pragma unroll
        for (int u = 0; u < 16; u++) hreg[u] = hxs[lane * 16 + u];
        const float* eb = enc + (long)b * Sz * Hz;
        for (int s = wave; s < Sz; s += 4) {
            const float* er = eb + (long)s * Hz + lane * 16;
            float sum = 0.f;
#pragma unroll
            for (int q = 0; q < 4; q++) {
                float4 e4 = *(const float4*)(er + q * 4);
                sum += e4.x*hreg[q*4] + e4.y*hreg[q*4+1] + e4.z*hreg[q*4+2] + e4.w*hreg[q*4+3];
            }
#pragma unroll
            for (int off = 32; off >= 1; off >>= 1) sum += __shfl_xor(sum, off);
            if (lane == 0) sc[s] = sum;
        }
        __syncthreads();
        if (tid < 64) {
            float v = (tid < Sz) ? sc[tid] : -3.402823e38f;
            float mx = v;
#pragma unroll
            for (int off = 32; off >= 1; off >>= 1) mx = fmaxf(mx, __shfl_xor(mx, off));
            float e = (tid < Sz) ? expf(v - mx) : 0.f;
            float ssum = e;
#pragma unroll
            for (int off = 32; off >= 1; off >>= 1) ssum += __shfl_xor(ssum, off);
            if (tid < Sz) aw[tid] = e / ssum;
        }
        __syncthreads();
        // context
        float* ctxT = ws + OFF_CTXT;
#pragma unroll
        for (int r = 0; r < 4; r++) {
            int h = tid + 256 * r;
            float a = 0.f;
            for (int s = 0; s < Sz; s++) a += aw[s] * eb[(long)s * Hz + h];
            ctxT[h * Bz + b] = a;
        }
    } else if (wid < 160) {
        if (!do_htred) return;
        int gid = (wid - 32) * 256 + tid;      // [0, 32768)
        int b = gid >> 10, h = gid & 1023;
        const float* hp = ws + OFF_HP + (long)b * KSPL * Hz;
        float s = 0.f;
#pragma unroll
        for (int ks = 0; ks < KSPL; ks++) s += hp[ks * Hz + h];
        ws[OFF_HXA + (long)(t - 1) * Bz * Hz + gid] = tanhf(s + bht[h]);
    } else {
        if (!do_gather) return;
        int gid = (wid - 160) * 256 + tid;     // [0, 16384)
        int k = gid >> 5, b = gid & 31;
        float* xhn = ws + OFF_XHT + (p ^ 1) * KXz * Bz;
        xhn[k * Bz + b] = emb[(long)tok[b * Tz + (t + 1)] * Dz + k];
    }
}

// vocab projection: C[1600][32000] = HXA_rows @ Wvoc^T + bvoc  (fp32, 128x128 tile, 8x8/thread)
__global__ __launch_bounds__(256) void k_voc(const float* hxa, const float* Wvoc,
                                             const float* bvoc, float* out) {
    int mt = blockIdx.x / 250, nt = blockIdx.x % 250;
    __shared__ float As[16][132];
    __shared__ float Bs[16][132];
    int tid = threadIdx.x;
    int ty = tid >> 4, tx = tid & 15;
    float acc[8][8];
#pragma unroll
    for (int i = 0; i < 8; i++)
#pragma unroll
        for (int j = 0; j < 8; j++) acc[i][j] = 0.f;

    for (int kb = 0; kb < Hz; kb += 16) {
        int f0 = tid * 2;
#pragma unroll
        for (int q = 0; q < 2; q++) {
            int f = f0 + q;
            int m = f >> 2, kq = (f & 3) * 4;
            int r = mt * 128 + m;
            float4 v = {0.f, 0.f, 0.f, 0.f};
            if (r < Bz * Tz) {
                int bb = r / Tz, tt = r % Tz;
                v = *(const float4*)(hxa + ((long)tt * Bz + bb) * Hz + kb + kq);
            }
            As[kq + 0][m] = v.x; As[kq + 1][m] = v.y; As[kq + 2][m] = v.z; As[kq + 3][m] = v.w;
            float4 w = *(const float4*)(Wvoc + (long)(nt * 128 + m) * Hz + kb + kq);
            Bs[kq + 0][m] = w.x; Bs[kq + 1][m] = w.y; Bs[kq + 2][m] = w.z; Bs[kq + 3][m] = w.w;
        }
        __syncthreads();
#pragma unroll
        for (int kk = 0; kk < 16; kk++) {
            float a[8], bb2[8];
            *(float4*)(a)     = *(float4*)&As[kk][ty * 8];
            *(float4*)(a + 4) = *(float4*)&As[kk][ty * 8 + 4];
            *(float4*)(bb2)     = *(float4*)&Bs[kk][tx * 8];
            *(float4*)(bb2 + 4) = *(float4*)&Bs[kk][tx * 8 + 4];
#pragma unroll
            for (int i = 0; i < 8; i++)
#pragma unroll
                for (int j = 0; j < 8; j++) acc[i][j] += a[i] * bb2[j];
        }
        __syncthreads();
    }
    int vcol = nt * 128 + tx * 8;
    float4 bv0 = *(const float4*)(bvoc + vcol);
    float4 bv1 = *(const float4*)(bvoc + vcol + 4);
#pragma unroll
    for (int i = 0; i < 8; i++) {
        int r = mt * 128 + ty * 8 + i;
        if (r >= Bz * Tz) break;
        float4 o0 = {acc[i][0] + bv0.x, acc[i][1] + bv0.y, acc[i][2] + bv0.z, acc[i][3] + bv0.w};
        float4 o1 = {acc[i][4] + bv1.x, acc[i][5] + bv1.y, acc[i][6] + bv1.z, acc[i][7] + bv1.w};
        *(float4*)(out + (long)r * Vz + vcol)     = o0;
        *(float4*)(out + (long)r * Vz + vcol + 4) = o1;
    }
}

__global__ __launch_bounds__(256) void k_argmax(const float* out, float* pred) {
    int r = blockIdx.x;
    const float* row = out + (long)r * Vz;
    int tid = threadIdx.x;
    float best = -3.402823e38f;
    int bi = 0;
    for (int v = tid; v < Vz; v += 256) {
        float x = row[v];
        if (x > best) { best = x; bi = v; }
    }
    __shared__ float sv[256];
    __shared__ int   si[256];
    sv[tid] = best; si[tid] = bi;
    __syncthreads();
    for (int s = 128; s > 0; s >>= 1) {
        if (tid < s) {
            float o = sv[tid + s]; int oi = si[tid + s];
            if (o > sv[tid] || (o == sv[tid] && oi < si[tid])) { sv[tid] = o; si[tid] = oi; }
        }
        __syncthreads();
    }
    if (tid == 0) pred[r] = (float)si[0];
}

extern "C" void kernel_launch(void* const* d_in, const int* in_sizes, int n_in,
                              void* d_out, int out_size, void* d_ws, size_t ws_size,
                              hipStream_t stream) {
    const int*   tok  = (const int*)d_in[0];
    const float* enc  = (const float*)d_in[1];
    const float* h0   = (const float*)d_in[2];
    const float* c0   = (const float*)d_in[3];
    const float* emb  = (const float*)d_in[6];
    const float* Wih  = (const float*)d_in[7];
    const float* Whh  = (const float*)d_in[8];
    const float* bih  = (const float*)d_in[9];
    const float* bhh  = (const float*)d_in[10];
    const float* Wht  = (const float*)d_in[11];
    const float* bht  = (const float*)d_in[12];
    const float* Wvoc = (const float*)d_in[13];
    const float* bvoc = (const float*)d_in[14];
    float* out = (float*)d_out;
    float* ws  = (float*)d_ws;

    k_init<<<320, 256, 0, stream>>>(ws, tok, emb, h0, c0);
    for (int t = 0; t < Tz; t++) {
        k_A<<<640, 256, 0, stream>>>(ws, Wih, Whh, Wht, t, 1, t > 0 ? 1 : 0);
        k_B<<<224, 256, 0, stream>>>(ws, bih, bhh, enc, emb, tok, bht, t, 1, t > 0 ? 1 : 0,
                                     (t + 1 < Tz) ? 1 : 0);
    }
    k_A<<<640, 256, 0, stream>>>(ws, Wih, Whh, Wht, Tz, 0, 1);
    k_B<<<224, 256, 0, stream>>>(ws, bih, bhh, enc, emb, tok, bht, Tz, 0, 1, 0);
    k_voc<<<13 * 250, 256, 0, stream>>>(ws + OFF_HXA, Wvoc, bvoc, out);
    k_argmax<<<1600, 256, 0, stream>>>(out, out + (long)Bz * Tz * Vz);
}